// Round 16
// baseline (77.669 us; speedup 1.0000x reference)
//
#include <hip/hip_runtime.h>
#include <math.h>

#define BB 4
#define TT 4096
#define CE 1024
#define CH 64
#define SCALE2 0.18033688011112042f   // (64^-0.5) / ln(2): exp(s/8) = exp2(s*SCALE2)
#define NQT 64          // TT/64 tiles
#define NZC 8           // colstats q-range split (4 blocks/CU = 32 waves, max)
#define NZP 6           // pv k-range split (768 blocks = 3 blocks/CU with 51 KB LDS)

typedef unsigned short ushort_t;
typedef __attribute__((ext_vector_type(8))) short bf16x8;   // 8 bf16 = 4 VGPR
typedef __attribute__((ext_vector_type(8))) unsigned short u16x8;
typedef __attribute__((ext_vector_type(4))) float f32x4;

__device__ __forceinline__ unsigned short f2bf(float f) {
    unsigned int x = __builtin_bit_cast(unsigned int, f);
    unsigned int r = x + 0x7fffu + ((x >> 16) & 1u);   // RNE
    return (unsigned short)(r >> 16);
}
__device__ __forceinline__ float bf2f(unsigned short u) {
    unsigned int x = ((unsigned int)u) << 16;
    return __builtin_bit_cast(float, x);
}

// stage a contiguous 64x64 bf16 tile into pad-68 LDS with 256 threads (tg = tid&255)
__device__ __forceinline__ void stage_tile(const ushort_t* __restrict__ src,
                                           ushort_t (*dst)[68], int tg)
{
#pragma unroll
    for (int i = 0; i < 2; ++i) {
        const int idx = i * 256 + tg;           // 0..511
        const int row = idx >> 3, c0 = (idx & 7) * 8;
        u16x8 v = *(const u16x8*)(src + (long)idx * 8);
        union { u16x8 v; uint2 q[2]; } uu; uu.v = v;
        *(uint2*)&dst[row][c0]     = uu.q[0];
        *(uint2*)&dst[row][c0 + 4] = uu.q[1];
    }
}

// same, with all 512 threads
__device__ __forceinline__ void stage_tile512(const ushort_t* __restrict__ src,
                                              ushort_t (*dst)[68], int tid)
{
    const int row = tid >> 3, c0 = (tid & 7) * 8;
    u16x8 v = *(const u16x8*)(src + (long)tid * 8);
    union { u16x8 v; uint2 q[2]; } uu; uu.v = v;
    *(uint2*)&dst[row][c0]     = uu.q[0];
    *(uint2*)&dst[row][c0 + 4] = uu.q[1];
}

// b64-pair fragment read from pad-68 LDS (bank = 2*lr+4*lg: uniform, minimal)
__device__ __forceinline__ bf16x8 frag68(const ushort_t* p) {
    union { bf16x8 v; uint2 q[2]; } uu;
    uu.q[0] = *(const uint2*)p;
    uu.q[1] = *(const uint2*)(p + 4);
    return uu.v;
}

// ---------------- build wt2, pre-tiled: wt2[(k>>5)*192*32 + c*32 + (k&31)] ----------------
__global__ __launch_bounds__(256)
void wt_build(const float* __restrict__ Wk, const float* __restrict__ Wq,
              const float* __restrict__ Wv, ushort_t* __restrict__ wt2)
{
    const int m = blockIdx.x, kt = blockIdx.y;
    const float* __restrict__ W = (m == 0) ? Wk : (m == 1 ? Wq : Wv);
    const int k0 = kt * 64;
    __shared__ float lds[64][65];
    const int cc = threadIdx.x & 63, g = threadIdx.x >> 6;
#pragma unroll
    for (int i = 0; i < 16; ++i) {
        const int r = g * 16 + i;
        lds[r][cc] = W[(k0 + r) * CH + cc];
    }
    __syncthreads();
    const int k = k0 + cc;
#pragma unroll
    for (int i = 0; i < 16; ++i) {
        const int c = g * 16 + i;
        wt2[((long)(k >> 5) * 192 + (m * 64 + c)) * 32 + (k & 31)] = f2bf(lds[cc][c]);
    }
}

// ---------------- projection: LDS GEMM, BM=32 x BN=192 x BK=64 ----------------
// Double-buffered LDS, ONE barrier per K-step; reg-prefetch one step ahead.
__global__ __launch_bounds__(512)
void proj_mfma(const float* __restrict__ x, const ushort_t* __restrict__ wt2,
               ushort_t* __restrict__ qb, ushort_t* __restrict__ kb, ushort_t* __restrict__ vb)
{
    const int tid = threadIdx.x;
    const int w = tid >> 6, l = tid & 63, lg = l >> 4, lr = l & 15;
    const int wr = w >> 2, wc = w & 3;
    const long t0 = (long)blockIdx.x * 32;

    __shared__ ushort_t As[2][32][68];
    __shared__ ushort_t Bs[2][192][68];

    f32x4 acc[3];
#pragma unroll
    for (int nf = 0; nf < 3; ++nf) acc[nf] = (f32x4){0.f, 0.f, 0.f, 0.f};

    const int arow = tid >> 4, acol = (tid & 15) * 4;
    const float* __restrict__ xsrc = x + (t0 + arow) * CE + acol;

    int bc[3], bh[3], bk[3];
#pragma unroll
    for (int i = 0; i < 3; ++i) {
        const int idx = i * 512 + tid;
        const int h = idx >= 768;
        const int j = idx - h * 768;
        bc[i] = j >> 2; bh[i] = h; bk[i] = (j & 3) * 8;
    }

    // prologue: step0 -> LDS buf0; step1 -> regs
    float4 a4 = *(const float4*)(xsrc);
    u16x8 bv[3];
#pragma unroll
    for (int i = 0; i < 3; ++i)
        bv[i] = *(const u16x8*)(wt2 + ((long)(bh[i]) * 192 + bc[i]) * 32 + bk[i]);
    {
        uint2 pk;
        pk.x = (unsigned)f2bf(a4.x) | ((unsigned)f2bf(a4.y) << 16);
        pk.y = (unsigned)f2bf(a4.z) | ((unsigned)f2bf(a4.w) << 16);
        *(uint2*)&As[0][arow][acol] = pk;
#pragma unroll
        for (int i = 0; i < 3; ++i) {
            union { u16x8 v; uint2 q[2]; } uu; uu.v = bv[i];
            ushort_t* d = &Bs[0][bc[i]][bh[i] * 32 + bk[i]];
            *(uint2*)d = uu.q[0];
            *(uint2*)(d + 4) = uu.q[1];
        }
    }
    a4 = *(const float4*)(xsrc + 64);
#pragma unroll
    for (int i = 0; i < 3; ++i)
        bv[i] = *(const u16x8*)(wt2 + ((long)(2 + bh[i]) * 192 + bc[i]) * 32 + bk[i]);
    __syncthreads();

    for (int step = 0; step < 16; ++step) {
        const int cur = step & 1;
        if (step + 1 < 16) {
            uint2 pk;
            pk.x = (unsigned)f2bf(a4.x) | ((unsigned)f2bf(a4.y) << 16);
            pk.y = (unsigned)f2bf(a4.z) | ((unsigned)f2bf(a4.w) << 16);
            *(uint2*)&As[cur ^ 1][arow][acol] = pk;
#pragma unroll
            for (int i = 0; i < 3; ++i) {
                union { u16x8 v; uint2 q[2]; } uu; uu.v = bv[i];
                ushort_t* d = &Bs[cur ^ 1][bc[i]][bh[i] * 32 + bk[i]];
                *(uint2*)d = uu.q[0];
                *(uint2*)(d + 4) = uu.q[1];
            }
        }
        if (step + 2 < 16) {
            a4 = *(const float4*)(xsrc + (step + 2) * 64);
            const int ktn = (step + 2) * 2;
#pragma unroll
            for (int i = 0; i < 3; ++i)
                bv[i] = *(const u16x8*)(wt2 + ((long)(ktn + bh[i]) * 192 + bc[i]) * 32 + bk[i]);
        }
#pragma unroll
        for (int h = 0; h < 2; ++h) {
            bf16x8 af = frag68(&As[cur][wr * 16 + lr][h * 32 + lg * 8]);
#pragma unroll
            for (int nf = 0; nf < 3; ++nf) {
                bf16x8 bf = frag68(&Bs[cur][wc * 48 + nf * 16 + lr][h * 32 + lg * 8]);
                acc[nf] = __builtin_amdgcn_mfma_f32_16x16x32_bf16(af, bf, acc[nf], 0, 0, 0);
            }
        }
        __syncthreads();   // single barrier: next buf published, cur-buf reads drained
    }

    ushort_t* Os = &Bs[0][0][0];
#pragma unroll
    for (int nf = 0; nf < 3; ++nf)
#pragma unroll
        for (int r = 0; r < 4; ++r)
            Os[(wr * 16 + lg * 4 + r) * 200 + wc * 48 + nf * 16 + lr] = f2bf(acc[nf][r]);
    __syncthreads();
    if (tid < 256) {
        const int row = tid >> 3, c0 = (tid & 7) * 8;
#pragma unroll
        for (int m = 0; m < 3; ++m) {
            u16x8 ov = *(const u16x8*)&Os[row * 200 + m * 64 + c0];
            ushort_t* __restrict__ outp = (m == 0) ? kb : (m == 1 ? qb : vb);
            *(u16x8*)(outp + (t0 + row) * CH + c0) = ov;
        }
    }
}

// ---------------- pass 1: per-column (k) expsum, 8 waves = 2 j-groups x 4 k-slices ----------------
// grid (BB, 32, NZC): kt pair (p, 63-p); group wg takes j = j0 + NZC*wg + 2*NZC*i.
__global__ __launch_bounds__(512)
void colstats_mfma(const ushort_t* __restrict__ qb, const ushort_t* __restrict__ kb,
                   float* __restrict__ pl)
{
    const int b = blockIdx.x, p = blockIdx.y, z = blockIdx.z;
    const int tid = threadIdx.x;
    const int w = tid >> 6, l = tid & 63, lg = l >> 4, lr = l & 15;
    const int wg = w >> 2, wc = w & 3, tg = tid & 255;
    const long baseT = (long)b * TT;
    const long NTT = (long)BB * TT;

    __shared__ ushort_t Ks[64][68], Qs[2][64][68];
    __shared__ float redc[4][64][5];

    for (int pass = 0; pass < 2; ++pass) {
        const int kt = pass ? (63 - p) : p;
        stage_tile512(kb + (baseT + (long)kt * 64) * CH, Ks, tid);
        __syncthreads();
        bf16x8 ka0 = frag68(&Ks[wc * 16 + lr][lg * 8]);
        bf16x8 ka1 = frag68(&Ks[wc * 16 + lr][32 + lg * 8]);

        float l_r[4] = {0.f, 0.f, 0.f, 0.f};

        const int j0 = kt + ((z - kt) & (NZC - 1));
        const int n0 = (j0 < NQT) ? ((NQT - 1 - j0) >> 4) + 1 : 0;   // stride 2*NZC = 16
        for (int i = 0; i < n0; ++i) {
            const int j = j0 + NZC * wg + 2 * NZC * i;
            const bool act = (j < NQT);
            if (act) stage_tile(qb + (baseT + (long)j * 64) * CH, Qs[wg], tg);
            __syncthreads();   // B1: Qs ready
            if (act) {
                const bool diag = (j == kt);
#pragma unroll
                for (int qf = 0; qf < 4; ++qf) {
                    bf16x8 b0 = frag68(&Qs[wg][qf * 16 + lr][lg * 8]);
                    bf16x8 b1 = frag68(&Qs[wg][qf * 16 + lr][32 + lg * 8]);
                    f32x4 s = {0.f, 0.f, 0.f, 0.f};
                    s = __builtin_amdgcn_mfma_f32_16x16x32_bf16(ka0, b0, s, 0, 0, 0);
                    s = __builtin_amdgcn_mfma_f32_16x16x32_bf16(ka1, b1, s, 0, 0, 0);
#pragma unroll
                    for (int r = 0; r < 4; ++r) {
                        float ev = exp2f(s[r] * SCALE2);
                        if (diag && (qf * 16 + lr) < (wc * 16 + lg * 4 + r)) ev = 0.f;
                        l_r[r] += ev;
                    }
                }
            }
            __syncthreads();   // B2: Qs reads drained before next stage
        }
        // combine the 2 j-groups, then sum over the 16-lane q dimension
        if (wg == 1) {
#pragma unroll
            for (int r = 0; r < 4; ++r) redc[wc][l][r] = l_r[r];
        }
        __syncthreads();
        if (wg == 0) {
#pragma unroll
            for (int r = 0; r < 4; ++r) {
                float lv = l_r[r] + redc[wc][l][r];
                for (int d = 1; d < 16; d <<= 1) lv += __shfl_xor(lv, d);
                if (lr == 0) {
                    const long k = (long)kt * 64 + wc * 16 + lg * 4 + r;
                    pl[(long)z * NTT + baseT + k] = lv;
                }
            }
        }
        __syncthreads();   // redc safe for next pass
    }
}

// ---------------- vtb2[b][jtile][c][t] = v[t][c] / sum_z pl[z][t]  (bf16, tile-major) ----------------
__global__ __launch_bounds__(256)
void vt_scale(const ushort_t* __restrict__ vb, const float* __restrict__ pl,
              ushort_t* __restrict__ vtb2)
{
    const int b = blockIdx.x;
    const int jt = blockIdx.y;
    const long t0 = (long)jt * 64;
    const int tid = threadIdx.x;
    __shared__ ushort_t lds[64][72];
    const long baseT = (long)b * TT;
    const long NTT = (long)BB * TT;
#pragma unroll
    for (int i = 0; i < 2; ++i) {
        const int t = i * 32 + (tid >> 3);
        const int c0 = (tid & 7) * 8;
        u16x8 v = *(const u16x8*)(vb + (baseT + t0 + t) * CH + c0);
        const long idx = baseT + t0 + t;
        float ls = pl[idx];
#pragma unroll
        for (int zz = 1; zz < NZC; ++zz) ls += pl[zz * NTT + idx];
        const float sc = 1.f / ls;
#pragma unroll
        for (int j = 0; j < 8; ++j) lds[c0 + j][t] = f2bf(bf2f(v[j]) * sc);
    }
    __syncthreads();
    ushort_t* __restrict__ dst = vtb2 + ((long)(b * 64 + jt)) * (64 * 64);
#pragma unroll
    for (int i = 0; i < 2; ++i) {
        const int c = i * 32 + (tid >> 3);
        const int tt0 = (tid & 7) * 8;
        u16x8 ov = *(const u16x8*)&lds[c][tt0];
        *(u16x8*)(dst + (long)c * 64 + tt0) = ov;
    }
}

// ---------------- pass 2: O^T partials (bf16), 8 waves = 2 j-groups x 4 slices ----------------
// grid (BB, 32, NZP). Slim LDS (51 KB -> 3 blocks/CU): group-0 P buffer aliases Qs
// (Q lives in registers after the hoist); redp aliases Ks (dead after the j-loop's final B2).
__global__ __launch_bounds__(512)
void pv_mfma(const ushort_t* __restrict__ qb, const ushort_t* __restrict__ kb,
             const ushort_t* __restrict__ vtb2, ushort_t* __restrict__ pout)
{
    const int b = blockIdx.x, p = blockIdx.y, z = blockIdx.z;
    const int tid = threadIdx.x;
    const int w = tid >> 6, l = tid & 63, lg = l >> 4, lr = l & 15;
    const int wg = w >> 2, wc = w & 3, tg = tid & 255;
    const long baseT = (long)b * TT;
    const long NTT = (long)BB * TT;

    __shared__ ushort_t Qs[64][68];        // Q stage; then group-0's P buffer
    __shared__ ushort_t Ks[2][64][68];     // K tiles; redp overlay after the loop
    __shared__ ushort_t Vs[2][64][68];
    __shared__ ushort_t Ps1[64][68];       // group-1's P buffer
    float (*redp)[64][17] = (float (*)[64][17])&Ks[0][0][0];   // 4*64*17*4B == 2*8704B

    for (int pass = 0; pass < 2; ++pass) {
        const int qt = pass ? (63 - p) : p;
        stage_tile512(qb + (baseT + (long)qt * 64) * CH, Qs, tid);
        __syncthreads();
        bf16x8 qf_[4][2];
#pragma unroll
        for (int qf = 0; qf < 4; ++qf) {
            qf_[qf][0] = frag68(&Qs[qf * 16 + lr][lg * 8]);
            qf_[qf][1] = frag68(&Qs[qf * 16 + lr][32 + lg * 8]);
        }
        f32x4 o[4];
#pragma unroll
        for (int qf = 0; qf < 4; ++qf) o[qf] = (f32x4){0.f, 0.f, 0.f, 0.f};

        ushort_t (*Pbuf)[68] = (wg == 0) ? Qs : Ps1;

        const int n0 = (qt >= z) ? ((qt - z) / (2 * NZP)) + 1 : 0;
        for (int i = 0; i < n0; ++i) {
            const int j = z + NZP * wg + 2 * NZP * i;
            const bool act = (j <= qt);
            if (act) {
                stage_tile(kb + (baseT + (long)j * 64) * CH, Ks[wg], tg);
                stage_tile(vtb2 + ((long)(b * 64 + j)) * (64 * 64), Vs[wg], tg);
            }
            __syncthreads();   // B1: Ks/Vs ready (and all Qs-hoist reads ordered before P writes)
            bf16x8 va0, va1;
            if (act) {
                bf16x8 ka0 = frag68(&Ks[wg][wc * 16 + lr][lg * 8]);
                bf16x8 ka1 = frag68(&Ks[wg][wc * 16 + lr][32 + lg * 8]);
                va0 = frag68(&Vs[wg][wc * 16 + lr][lg * 8]);
                va1 = frag68(&Vs[wg][wc * 16 + lr][32 + lg * 8]);
                const bool diag = (j == qt);
#pragma unroll
                for (int qf = 0; qf < 4; ++qf) {
                    f32x4 s = {0.f, 0.f, 0.f, 0.f};
                    s = __builtin_amdgcn_mfma_f32_16x16x32_bf16(ka0, qf_[qf][0], s, 0, 0, 0);
                    s = __builtin_amdgcn_mfma_f32_16x16x32_bf16(ka1, qf_[qf][1], s, 0, 0, 0);
                    unsigned short e[4];
#pragma unroll
                    for (int r = 0; r < 4; ++r) {
                        float ev = exp2f(s[r] * SCALE2);
                        if (diag && (qf * 16 + lr) < (wc * 16 + lg * 4 + r)) ev = 0.f;
                        e[r] = f2bf(ev);
                    }
                    uint2 pk;
                    pk.x = (unsigned)e[0] | ((unsigned)e[1] << 16);
                    pk.y = (unsigned)e[2] | ((unsigned)e[3] << 16);
                    *(uint2*)&Pbuf[qf * 16 + lr][wc * 16 + lg * 4] = pk;
                }
            }
            __syncthreads();   // B2: Ps ready (Ks/Vs reg-loads drained)
            if (act) {
#pragma unroll
                for (int qf = 0; qf < 4; ++qf) {
                    bf16x8 p0 = frag68(&Pbuf[qf * 16 + lr][lg * 8]);
                    bf16x8 p1 = frag68(&Pbuf[qf * 16 + lr][32 + lg * 8]);
                    o[qf] = __builtin_amdgcn_mfma_f32_16x16x32_bf16(va0, p0, o[qf], 0, 0, 0);
                    o[qf] = __builtin_amdgcn_mfma_f32_16x16x32_bf16(va1, p1, o[qf], 0, 0, 0);
                }
            }
        }
        // combine the 2 j-groups' partial O (redp overlays dead Ks), then store bf16
        if (wg == 1) {
#pragma unroll
            for (int qf = 0; qf < 4; ++qf)
#pragma unroll
                for (int r = 0; r < 4; ++r) redp[wc][l][qf * 4 + r] = o[qf][r];
        }
        __syncthreads();
        if (wg == 0) {
            ushort_t* pz = pout + ((long)z * NTT + baseT + (long)qt * 64) * CH;
#pragma unroll
            for (int qf = 0; qf < 4; ++qf) {
                f32x4 ov = o[qf];
#pragma unroll
                for (int r = 0; r < 4; ++r) ov[r] += redp[wc][l][qf * 4 + r];
                uint2 pk;
                pk.x = (unsigned)f2bf(ov[0]) | ((unsigned)f2bf(ov[1]) << 16);
                pk.y = (unsigned)f2bf(ov[2]) | ((unsigned)f2bf(ov[3]) << 16);
                *(uint2*)(pz + (long)(qf * 16 + lr) * CH + wc * 16 + lg * 4) = pk;
            }
        }
        __syncthreads();   // pass end: all aliased buffers safe to restage
    }
}

// ---------------- sum the NZP bf16 partial outputs -> f32 ----------------
__global__ __launch_bounds__(256)
void finalize_out(const ushort_t* __restrict__ pout, float* __restrict__ out)
{
    const long i = (long)blockIdx.x * 256 + threadIdx.x;   // index over groups of 4 elems
    const long ne = (long)BB * TT * CH;                    // elems per partial
    float s0 = 0.f, s1 = 0.f, s2 = 0.f, s3 = 0.f;
#pragma unroll
    for (int zz = 0; zz < NZP; ++zz) {
        uint2 a = *(const uint2*)(pout + zz * ne + i * 4);
        s0 += bf2f((unsigned short)(a.x & 0xffffu));
        s1 += bf2f((unsigned short)(a.x >> 16));
        s2 += bf2f((unsigned short)(a.y & 0xffffu));
        s3 += bf2f((unsigned short)(a.y >> 16));
    }
    float4 r; r.x = s0; r.y = s1; r.z = s2; r.w = s3;
    reinterpret_cast<float4*>(out)[i] = r;
}

extern "C" void kernel_launch(void* const* d_in, const int* in_sizes, int n_in,
                              void* d_out, int out_size, void* d_ws, size_t ws_size,
                              hipStream_t stream)
{
    const float* x  = (const float*)d_in[0];
    const float* Wk = (const float*)d_in[1];
    const float* Wq = (const float*)d_in[2];
    const float* Wv = (const float*)d_in[3];
    float* out = (float*)d_out;

    const size_t NT = (size_t)BB * TT;   // 16384
    ushort_t* qb   = (ushort_t*)d_ws;    // NT*CH bf16
    ushort_t* kb   = qb + NT * CH;
    ushort_t* vb   = kb + NT * CH;
    ushort_t* vtb2 = vb + NT * CH;
    ushort_t* wt2  = vtb2 + NT * CH;        // 192*1024 bf16
    float* pl      = (float*)(wt2 + 192 * CE);   // NZC*NT f32
    ushort_t* pout = (ushort_t*)(pl + NZC * NT); // NZP*NT*CH bf16

    hipLaunchKernelGGL(wt_build, dim3(3, 16), dim3(256), 0, stream,
                       Wk, Wq, Wv, wt2);
    hipLaunchKernelGGL(proj_mfma, dim3(NT / 32), dim3(512), 0, stream,
                       x, wt2, qb, kb, vb);
    hipLaunchKernelGGL(colstats_mfma, dim3(BB, NQT / 2, NZC), dim3(512), 0, stream,
                       qb, kb, pl);
    hipLaunchKernelGGL(vt_scale, dim3(BB, TT / 64), dim3(256), 0, stream,
                       vb, pl, vtb2);
    hipLaunchKernelGGL(pv_mfma, dim3(BB, NQT / 2, NZP), dim3(512), 0, stream,
                       qb, kb, vtb2, pout);
    hipLaunchKernelGGL(finalize_out, dim3(NT * CH / 4 / 256), dim3(256), 0, stream,
                       pout, out);
}

// Round 17
// 74.408 us; speedup vs baseline: 1.0438x; 1.0438x over previous
//
#include <hip/hip_runtime.h>
#include <math.h>

#define BB 4
#define TT 4096
#define CE 1024
#define CH 64
#define SCALE2 0.18033688011112042f   // (64^-0.5) / ln(2): exp(s/8) = exp2(s*SCALE2)
#define NQT 64          // TT/64 tiles
#define NZC 8           // colstats q-range split (4 blocks/CU = 32 waves, max)
#define NZP 4           // pv k-range split

typedef unsigned short ushort_t;
typedef __attribute__((ext_vector_type(8))) short bf16x8;   // 8 bf16 = 4 VGPR
typedef __attribute__((ext_vector_type(8))) unsigned short u16x8;
typedef __attribute__((ext_vector_type(4))) float f32x4;

__device__ __forceinline__ unsigned short f2bf(float f) {
    unsigned int x = __builtin_bit_cast(unsigned int, f);
    unsigned int r = x + 0x7fffu + ((x >> 16) & 1u);   // RNE
    return (unsigned short)(r >> 16);
}
__device__ __forceinline__ float bf2f(unsigned short u) {
    unsigned int x = ((unsigned int)u) << 16;
    return __builtin_bit_cast(float, x);
}

// stage a contiguous 64x64 bf16 tile into pad-68 LDS with 256 threads (tg = tid&255)
__device__ __forceinline__ void stage_tile(const ushort_t* __restrict__ src,
                                           ushort_t (*dst)[68], int tg)
{
#pragma unroll
    for (int i = 0; i < 2; ++i) {
        const int idx = i * 256 + tg;           // 0..511
        const int row = idx >> 3, c0 = (idx & 7) * 8;
        u16x8 v = *(const u16x8*)(src + (long)idx * 8);
        union { u16x8 v; uint2 q[2]; } uu; uu.v = v;
        *(uint2*)&dst[row][c0]     = uu.q[0];
        *(uint2*)&dst[row][c0 + 4] = uu.q[1];
    }
}

// same, with all 512 threads
__device__ __forceinline__ void stage_tile512(const ushort_t* __restrict__ src,
                                              ushort_t (*dst)[68], int tid)
{
    const int row = tid >> 3, c0 = (tid & 7) * 8;
    u16x8 v = *(const u16x8*)(src + (long)tid * 8);
    union { u16x8 v; uint2 q[2]; } uu; uu.v = v;
    *(uint2*)&dst[row][c0]     = uu.q[0];
    *(uint2*)&dst[row][c0 + 4] = uu.q[1];
}

// b64-pair fragment read from pad-68 LDS (bank = 2*lr+4*lg: uniform, minimal)
__device__ __forceinline__ bf16x8 frag68(const ushort_t* p) {
    union { bf16x8 v; uint2 q[2]; } uu;
    uu.q[0] = *(const uint2*)p;
    uu.q[1] = *(const uint2*)(p + 4);
    return uu.v;
}

// ---------------- build wt2, pre-tiled: wt2[(k>>5)*192*32 + c*32 + (k&31)] ----------------
__global__ __launch_bounds__(256)
void wt_build(const float* __restrict__ Wk, const float* __restrict__ Wq,
              const float* __restrict__ Wv, ushort_t* __restrict__ wt2)
{
    const int m = blockIdx.x, kt = blockIdx.y;
    const float* __restrict__ W = (m == 0) ? Wk : (m == 1 ? Wq : Wv);
    const int k0 = kt * 64;
    __shared__ float lds[64][65];
    const int cc = threadIdx.x & 63, g = threadIdx.x >> 6;
#pragma unroll
    for (int i = 0; i < 16; ++i) {
        const int r = g * 16 + i;
        lds[r][cc] = W[(k0 + r) * CH + cc];
    }
    __syncthreads();
    const int k = k0 + cc;
#pragma unroll
    for (int i = 0; i < 16; ++i) {
        const int c = g * 16 + i;
        wt2[((long)(k >> 5) * 192 + (m * 64 + c)) * 32 + (k & 31)] = f2bf(lds[cc][c]);
    }
}

// ---------------- projection: LDS GEMM, BM=32 x BN=192 x BK=64 ----------------
// LDS dbuf + 2 register sets: loads for step i+3 issue at step i (in flight ~2 iters).
__global__ __launch_bounds__(512)
void proj_mfma(const float* __restrict__ x, const ushort_t* __restrict__ wt2,
               ushort_t* __restrict__ qb, ushort_t* __restrict__ kb, ushort_t* __restrict__ vb)
{
    const int tid = threadIdx.x;
    const int w = tid >> 6, l = tid & 63, lg = l >> 4, lr = l & 15;
    const int wr = w >> 2, wc = w & 3;
    const long t0 = (long)blockIdx.x * 32;

    __shared__ ushort_t As[2][32][68];
    __shared__ ushort_t Bs[2][192][68];

    f32x4 acc[3];
#pragma unroll
    for (int nf = 0; nf < 3; ++nf) acc[nf] = (f32x4){0.f, 0.f, 0.f, 0.f};

    const int arow = tid >> 4, acol = (tid & 15) * 4;
    const float* __restrict__ xsrc = x + (t0 + arow) * CE + acol;

    int bc[3], bh[3], bk[3];
#pragma unroll
    for (int i = 0; i < 3; ++i) {
        const int idx = i * 512 + tid;
        const int h = idx >= 768;
        const int j = idx - h * 768;
        bc[i] = j >> 2; bh[i] = h; bk[i] = (j & 3) * 8;
    }

    // prologue: step0 -> LDS buf0 directly; step1 -> regs[0]; step2 -> regs[1]
    {
        float4 t = *(const float4*)(xsrc);
        uint2 pk;
        pk.x = (unsigned)f2bf(t.x) | ((unsigned)f2bf(t.y) << 16);
        pk.y = (unsigned)f2bf(t.z) | ((unsigned)f2bf(t.w) << 16);
        *(uint2*)&As[0][arow][acol] = pk;
#pragma unroll
        for (int i = 0; i < 3; ++i) {
            u16x8 tb = *(const u16x8*)(wt2 + ((long)(bh[i]) * 192 + bc[i]) * 32 + bk[i]);
            union { u16x8 v; uint2 q[2]; } uu; uu.v = tb;
            ushort_t* d = &Bs[0][bc[i]][bh[i] * 32 + bk[i]];
            *(uint2*)d = uu.q[0];
            *(uint2*)(d + 4) = uu.q[1];
        }
    }
    float4 a4[2];
    u16x8 bv[2][3];
#pragma unroll
    for (int s = 0; s < 2; ++s) {
        a4[s] = *(const float4*)(xsrc + (s + 1) * 64);
        const int ktn = (s + 1) * 2;
#pragma unroll
        for (int i = 0; i < 3; ++i)
            bv[s][i] = *(const u16x8*)(wt2 + ((long)(ktn + bh[i]) * 192 + bc[i]) * 32 + bk[i]);
    }
    __syncthreads();

    for (int step = 0; step < 16; ++step) {
        const int cur = step & 1;
        // write reg set (holds step+1) -> other LDS buffer
        if (step + 1 < 16) {
            uint2 pk;
            pk.x = (unsigned)f2bf(a4[cur].x) | ((unsigned)f2bf(a4[cur].y) << 16);
            pk.y = (unsigned)f2bf(a4[cur].z) | ((unsigned)f2bf(a4[cur].w) << 16);
            *(uint2*)&As[cur ^ 1][arow][acol] = pk;
#pragma unroll
            for (int i = 0; i < 3; ++i) {
                union { u16x8 v; uint2 q[2]; } uu; uu.v = bv[cur][i];
                ushort_t* d = &Bs[cur ^ 1][bc[i]][bh[i] * 32 + bk[i]];
                *(uint2*)d = uu.q[0];
                *(uint2*)(d + 4) = uu.q[1];
            }
        }
        // issue loads for step+3 into the just-freed reg set
        if (step + 3 < 16) {
            a4[cur] = *(const float4*)(xsrc + (step + 3) * 64);
            const int ktn = (step + 3) * 2;
#pragma unroll
            for (int i = 0; i < 3; ++i)
                bv[cur][i] = *(const u16x8*)(wt2 + ((long)(ktn + bh[i]) * 192 + bc[i]) * 32 + bk[i]);
        }
        // compute current buffer
#pragma unroll
        for (int h = 0; h < 2; ++h) {
            bf16x8 af = frag68(&As[cur][wr * 16 + lr][h * 32 + lg * 8]);
#pragma unroll
            for (int nf = 0; nf < 3; ++nf) {
                bf16x8 bf = frag68(&Bs[cur][wc * 48 + nf * 16 + lr][h * 32 + lg * 8]);
                acc[nf] = __builtin_amdgcn_mfma_f32_16x16x32_bf16(af, bf, acc[nf], 0, 0, 0);
            }
        }
        __syncthreads();   // single barrier: next buf published, cur-buf reads drained
    }

    ushort_t* Os = &Bs[0][0][0];
#pragma unroll
    for (int nf = 0; nf < 3; ++nf)
#pragma unroll
        for (int r = 0; r < 4; ++r)
            Os[(wr * 16 + lg * 4 + r) * 200 + wc * 48 + nf * 16 + lr] = f2bf(acc[nf][r]);
    __syncthreads();
    if (tid < 256) {
        const int row = tid >> 3, c0 = (tid & 7) * 8;
#pragma unroll
        for (int m = 0; m < 3; ++m) {
            u16x8 ov = *(const u16x8*)&Os[row * 200 + m * 64 + c0];
            ushort_t* __restrict__ outp = (m == 0) ? kb : (m == 1 ? qb : vb);
            *(u16x8*)(outp + (t0 + row) * CH + c0) = ov;
        }
    }
}

// ---------------- pass 1: per-column (k) expsum, 8 waves = 2 j-groups x 4 k-slices ----------------
// grid (BB, 32, NZC): kt pair (p, 63-p); group wg takes j = j0 + NZC*wg + 2*NZC*i.
__global__ __launch_bounds__(512)
void colstats_mfma(const ushort_t* __restrict__ qb, const ushort_t* __restrict__ kb,
                   float* __restrict__ pl)
{
    const int b = blockIdx.x, p = blockIdx.y, z = blockIdx.z;
    const int tid = threadIdx.x;
    const int w = tid >> 6, l = tid & 63, lg = l >> 4, lr = l & 15;
    const int wg = w >> 2, wc = w & 3, tg = tid & 255;
    const long baseT = (long)b * TT;
    const long NTT = (long)BB * TT;

    __shared__ ushort_t Ks[64][68], Qs[2][64][68];
    __shared__ float redc[4][64][5];

    for (int pass = 0; pass < 2; ++pass) {
        const int kt = pass ? (63 - p) : p;
        stage_tile512(kb + (baseT + (long)kt * 64) * CH, Ks, tid);
        __syncthreads();
        bf16x8 ka0 = frag68(&Ks[wc * 16 + lr][lg * 8]);
        bf16x8 ka1 = frag68(&Ks[wc * 16 + lr][32 + lg * 8]);

        float l_r[4] = {0.f, 0.f, 0.f, 0.f};

        const int j0 = kt + ((z - kt) & (NZC - 1));
        const int n0 = (j0 < NQT) ? ((NQT - 1 - j0) >> 4) + 1 : 0;   // stride 2*NZC = 16
        for (int i = 0; i < n0; ++i) {
            const int j = j0 + NZC * wg + 2 * NZC * i;
            const bool act = (j < NQT);
            if (act) stage_tile(qb + (baseT + (long)j * 64) * CH, Qs[wg], tg);
            __syncthreads();   // B1: Qs ready
            if (act) {
                const bool diag = (j == kt);
#pragma unroll
                for (int qf = 0; qf < 4; ++qf) {
                    bf16x8 b0 = frag68(&Qs[wg][qf * 16 + lr][lg * 8]);
                    bf16x8 b1 = frag68(&Qs[wg][qf * 16 + lr][32 + lg * 8]);
                    f32x4 s = {0.f, 0.f, 0.f, 0.f};
                    s = __builtin_amdgcn_mfma_f32_16x16x32_bf16(ka0, b0, s, 0, 0, 0);
                    s = __builtin_amdgcn_mfma_f32_16x16x32_bf16(ka1, b1, s, 0, 0, 0);
#pragma unroll
                    for (int r = 0; r < 4; ++r) {
                        float ev = exp2f(s[r] * SCALE2);
                        if (diag && (qf * 16 + lr) < (wc * 16 + lg * 4 + r)) ev = 0.f;
                        l_r[r] += ev;
                    }
                }
            }
            __syncthreads();   // B2: Qs reads drained before next stage
        }
        // combine the 2 j-groups, then sum over the 16-lane q dimension
        if (wg == 1) {
#pragma unroll
            for (int r = 0; r < 4; ++r) redc[wc][l][r] = l_r[r];
        }
        __syncthreads();
        if (wg == 0) {
#pragma unroll
            for (int r = 0; r < 4; ++r) {
                float lv = l_r[r] + redc[wc][l][r];
                for (int d = 1; d < 16; d <<= 1) lv += __shfl_xor(lv, d);
                if (lr == 0) {
                    const long k = (long)kt * 64 + wc * 16 + lg * 4 + r;
                    pl[(long)z * NTT + baseT + k] = lv;
                }
            }
        }
        __syncthreads();   // redc safe for next pass
    }
}

// ---------------- vtb2[b][jtile][c][t] = v[t][c] / sum_z pl[z][t]  (bf16, tile-major) ----------------
__global__ __launch_bounds__(256)
void vt_scale(const ushort_t* __restrict__ vb, const float* __restrict__ pl,
              ushort_t* __restrict__ vtb2)
{
    const int b = blockIdx.x;
    const int jt = blockIdx.y;
    const long t0 = (long)jt * 64;
    const int tid = threadIdx.x;
    __shared__ ushort_t lds[64][72];
    const long baseT = (long)b * TT;
    const long NTT = (long)BB * TT;
#pragma unroll
    for (int i = 0; i < 2; ++i) {
        const int t = i * 32 + (tid >> 3);
        const int c0 = (tid & 7) * 8;
        u16x8 v = *(const u16x8*)(vb + (baseT + t0 + t) * CH + c0);
        const long idx = baseT + t0 + t;
        float ls = pl[idx];
#pragma unroll
        for (int zz = 1; zz < NZC; ++zz) ls += pl[zz * NTT + idx];
        const float sc = 1.f / ls;
#pragma unroll
        for (int j = 0; j < 8; ++j) lds[c0 + j][t] = f2bf(bf2f(v[j]) * sc);
    }
    __syncthreads();
    ushort_t* __restrict__ dst = vtb2 + ((long)(b * 64 + jt)) * (64 * 64);
#pragma unroll
    for (int i = 0; i < 2; ++i) {
        const int c = i * 32 + (tid >> 3);
        const int tt0 = (tid & 7) * 8;
        u16x8 ov = *(const u16x8*)&lds[c][tt0];
        *(u16x8*)(dst + (long)c * 64 + tt0) = ov;
    }
}

// ---------------- pass 2: O^T partials (bf16), 8 waves = 2 j-groups x 4 slices ----------------
// grid (BB, 32, NZP).
__global__ __launch_bounds__(512)
void pv_mfma(const ushort_t* __restrict__ qb, const ushort_t* __restrict__ kb,
             const ushort_t* __restrict__ vtb2, ushort_t* __restrict__ pout)
{
    const int b = blockIdx.x, p = blockIdx.y, z = blockIdx.z;
    const int tid = threadIdx.x;
    const int w = tid >> 6, l = tid & 63, lg = l >> 4, lr = l & 15;
    const int wg = w >> 2, wc = w & 3, tg = tid & 255;
    const long baseT = (long)b * TT;
    const long NTT = (long)BB * TT;

    __shared__ ushort_t Qs[64][68], Ks[2][64][68], Vs[2][64][68], Ps[2][64][68];
    __shared__ float redp[4][64][17];

    for (int pass = 0; pass < 2; ++pass) {
        const int qt = pass ? (63 - p) : p;
        stage_tile512(qb + (baseT + (long)qt * 64) * CH, Qs, tid);
        __syncthreads();
        bf16x8 qf_[4][2];
#pragma unroll
        for (int qf = 0; qf < 4; ++qf) {
            qf_[qf][0] = frag68(&Qs[qf * 16 + lr][lg * 8]);
            qf_[qf][1] = frag68(&Qs[qf * 16 + lr][32 + lg * 8]);
        }
        f32x4 o[4];
#pragma unroll
        for (int qf = 0; qf < 4; ++qf) o[qf] = (f32x4){0.f, 0.f, 0.f, 0.f};

        const int n0 = (qt >= z) ? ((qt - z) >> 3) + 1 : 0;
        for (int i = 0; i < n0; ++i) {
            const int j = z + 4 * wg + 8 * i;
            const bool act = (j <= qt);
            if (act) {
                stage_tile(kb + (baseT + (long)j * 64) * CH, Ks[wg], tg);
                stage_tile(vtb2 + ((long)(b * 64 + j)) * (64 * 64), Vs[wg], tg);
            }
            __syncthreads();   // B1: Ks/Vs ready
            bf16x8 va0, va1;
            if (act) {
                bf16x8 ka0 = frag68(&Ks[wg][wc * 16 + lr][lg * 8]);
                bf16x8 ka1 = frag68(&Ks[wg][wc * 16 + lr][32 + lg * 8]);
                va0 = frag68(&Vs[wg][wc * 16 + lr][lg * 8]);
                va1 = frag68(&Vs[wg][wc * 16 + lr][32 + lg * 8]);
                const bool diag = (j == qt);
#pragma unroll
                for (int qf = 0; qf < 4; ++qf) {
                    f32x4 s = {0.f, 0.f, 0.f, 0.f};
                    s = __builtin_amdgcn_mfma_f32_16x16x32_bf16(ka0, qf_[qf][0], s, 0, 0, 0);
                    s = __builtin_amdgcn_mfma_f32_16x16x32_bf16(ka1, qf_[qf][1], s, 0, 0, 0);
                    unsigned short e[4];
#pragma unroll
                    for (int r = 0; r < 4; ++r) {
                        float ev = exp2f(s[r] * SCALE2);
                        if (diag && (qf * 16 + lr) < (wc * 16 + lg * 4 + r)) ev = 0.f;
                        e[r] = f2bf(ev);
                    }
                    uint2 pk;
                    pk.x = (unsigned)e[0] | ((unsigned)e[1] << 16);
                    pk.y = (unsigned)e[2] | ((unsigned)e[3] << 16);
                    *(uint2*)&Ps[wg][qf * 16 + lr][wc * 16 + lg * 4] = pk;
                }
            }
            __syncthreads();   // B2: Ps ready (Ks/Vs reg-loads drained)
            if (act) {
#pragma unroll
                for (int qf = 0; qf < 4; ++qf) {
                    bf16x8 p0 = frag68(&Ps[wg][qf * 16 + lr][lg * 8]);
                    bf16x8 p1 = frag68(&Ps[wg][qf * 16 + lr][32 + lg * 8]);
                    o[qf] = __builtin_amdgcn_mfma_f32_16x16x32_bf16(va0, p0, o[qf], 0, 0, 0);
                    o[qf] = __builtin_amdgcn_mfma_f32_16x16x32_bf16(va1, p1, o[qf], 0, 0, 0);
                }
            }
        }
        // combine the 2 j-groups' partial O, then store as bf16
        if (wg == 1) {
#pragma unroll
            for (int qf = 0; qf < 4; ++qf)
#pragma unroll
                for (int r = 0; r < 4; ++r) redp[wc][l][qf * 4 + r] = o[qf][r];
        }
        __syncthreads();
        if (wg == 0) {
            ushort_t* pz = pout + ((long)z * NTT + baseT + (long)qt * 64) * CH;
#pragma unroll
            for (int qf = 0; qf < 4; ++qf) {
                f32x4 ov = o[qf];
#pragma unroll
                for (int r = 0; r < 4; ++r) ov[r] += redp[wc][l][qf * 4 + r];
                uint2 pk;
                pk.x = (unsigned)f2bf(ov[0]) | ((unsigned)f2bf(ov[1]) << 16);
                pk.y = (unsigned)f2bf(ov[2]) | ((unsigned)f2bf(ov[3]) << 16);
                *(uint2*)(pz + (long)(qf * 16 + lr) * CH + wc * 16 + lg * 4) = pk;
            }
        }
        __syncthreads();   // redp safe for next pass
    }
}

// ---------------- sum the NZP bf16 partial outputs -> f32 ----------------
__global__ __launch_bounds__(256)
void finalize_out(const ushort_t* __restrict__ pout, float* __restrict__ out)
{
    const long i = (long)blockIdx.x * 256 + threadIdx.x;   // index over groups of 4 elems
    const long ne = (long)BB * TT * CH;                    // elems per partial
    float s0 = 0.f, s1 = 0.f, s2 = 0.f, s3 = 0.f;
#pragma unroll
    for (int zz = 0; zz < NZP; ++zz) {
        uint2 a = *(const uint2*)(pout + zz * ne + i * 4);
        s0 += bf2f((unsigned short)(a.x & 0xffffu));
        s1 += bf2f((unsigned short)(a.x >> 16));
        s2 += bf2f((unsigned short)(a.y & 0xffffu));
        s3 += bf2f((unsigned short)(a.y >> 16));
    }
    float4 r; r.x = s0; r.y = s1; r.z = s2; r.w = s3;
    reinterpret_cast<float4*>(out)[i] = r;
}

extern "C" void kernel_launch(void* const* d_in, const int* in_sizes, int n_in,
                              void* d_out, int out_size, void* d_ws, size_t ws_size,
                              hipStream_t stream)
{
    const float* x  = (const float*)d_in[0];
    const float* Wk = (const float*)d_in[1];
    const float* Wq = (const float*)d_in[2];
    const float* Wv = (const float*)d_in[3];
    float* out = (float*)d_out;

    const size_t NT = (size_t)BB * TT;   // 16384
    ushort_t* qb   = (ushort_t*)d_ws;    // NT*CH bf16
    ushort_t* kb   = qb + NT * CH;
    ushort_t* vb   = kb + NT * CH;
    ushort_t* vtb2 = vb + NT * CH;
    ushort_t* wt2  = vtb2 + NT * CH;        // 192*1024 bf16
    float* pl      = (float*)(wt2 + 192 * CE);   // NZC*NT f32
    ushort_t* pout = (ushort_t*)(pl + NZC * NT); // NZP*NT*CH bf16

    hipLaunchKernelGGL(wt_build, dim3(3, 16), dim3(256), 0, stream,
                       Wk, Wq, Wv, wt2);
    hipLaunchKernelGGL(proj_mfma, dim3(NT / 32), dim3(512), 0, stream,
                       x, wt2, qb, kb, vb);
    hipLaunchKernelGGL(colstats_mfma, dim3(BB, NQT / 2, NZC), dim3(512), 0, stream,
                       qb, kb, pl);
    hipLaunchKernelGGL(vt_scale, dim3(BB, TT / 64), dim3(256), 0, stream,
                       vb, pl, vtb2);
    hipLaunchKernelGGL(pv_mfma, dim3(BB, NQT / 2, NZP), dim3(512), 0, stream,
                       qb, kb, vtb2, pout);
    hipLaunchKernelGGL(finalize_out, dim3(NT * CH / 4 / 256), dim3(256), 0, stream,
                       pout, out);
}

// Round 18
// 71.889 us; speedup vs baseline: 1.0804x; 1.0350x over previous
//
#include <hip/hip_runtime.h>
#include <math.h>

#define BB 4
#define TT 4096
#define CE 1024
#define CH 64
#define SCALE2 0.18033688011112042f   // (64^-0.5) / ln(2): exp(s/8) = exp2(s*SCALE2)
#define NQT 64          // TT/64 tiles
#define NZC 8           // colstats q-range split (4 blocks/CU = 32 waves, max)
#define NZP 4           // pv k-range split

typedef unsigned short ushort_t;
typedef __attribute__((ext_vector_type(8))) short bf16x8;   // 8 bf16 = 4 VGPR
typedef __attribute__((ext_vector_type(8))) unsigned short u16x8;
typedef __attribute__((ext_vector_type(4))) float f32x4;

__device__ __forceinline__ unsigned short f2bf(float f) {
    unsigned int x = __builtin_bit_cast(unsigned int, f);
    unsigned int r = x + 0x7fffu + ((x >> 16) & 1u);   // RNE
    return (unsigned short)(r >> 16);
}
__device__ __forceinline__ float bf2f(unsigned short u) {
    unsigned int x = ((unsigned int)u) << 16;
    return __builtin_bit_cast(float, x);
}
// HW packed conversion: dst.lo = bf16(lo), dst.hi = bf16(hi); RNE == f2bf
__device__ __forceinline__ unsigned cvt_pk_bf16(float lo, float hi) {
    unsigned r;
    asm("v_cvt_pk_bf16_f32 %0, %1, %2" : "=v"(r) : "v"(lo), "v"(hi));
    return r;
}

// stage a contiguous 64x64 bf16 tile into pad-68 LDS with 256 threads (tg = tid&255)
__device__ __forceinline__ void stage_tile(const ushort_t* __restrict__ src,
                                           ushort_t (*dst)[68], int tg)
{
#pragma unroll
    for (int i = 0; i < 2; ++i) {
        const int idx = i * 256 + tg;           // 0..511
        const int row = idx >> 3, c0 = (idx & 7) * 8;
        u16x8 v = *(const u16x8*)(src + (long)idx * 8);
        union { u16x8 v; uint2 q[2]; } uu; uu.v = v;
        *(uint2*)&dst[row][c0]     = uu.q[0];
        *(uint2*)&dst[row][c0 + 4] = uu.q[1];
    }
}

// same, with all 512 threads
__device__ __forceinline__ void stage_tile512(const ushort_t* __restrict__ src,
                                              ushort_t (*dst)[68], int tid)
{
    const int row = tid >> 3, c0 = (tid & 7) * 8;
    u16x8 v = *(const u16x8*)(src + (long)tid * 8);
    union { u16x8 v; uint2 q[2]; } uu; uu.v = v;
    *(uint2*)&dst[row][c0]     = uu.q[0];
    *(uint2*)&dst[row][c0 + 4] = uu.q[1];
}

// b64-pair fragment read from pad-68 LDS (bank = 2*lr+4*lg: uniform, minimal)
__device__ __forceinline__ bf16x8 frag68(const ushort_t* p) {
    union { bf16x8 v; uint2 q[2]; } uu;
    uu.q[0] = *(const uint2*)p;
    uu.q[1] = *(const uint2*)(p + 4);
    return uu.v;
}

// ---------------- build wt2, pre-tiled: wt2[(k>>5)*192*32 + c*32 + (k&31)] ----------------
__global__ __launch_bounds__(256)
void wt_build(const float* __restrict__ Wk, const float* __restrict__ Wq,
              const float* __restrict__ Wv, ushort_t* __restrict__ wt2)
{
    const int m = blockIdx.x, kt = blockIdx.y;
    const float* __restrict__ W = (m == 0) ? Wk : (m == 1 ? Wq : Wv);
    const int k0 = kt * 64;
    __shared__ float lds[64][65];
    const int cc = threadIdx.x & 63, g = threadIdx.x >> 6;
#pragma unroll
    for (int i = 0; i < 16; ++i) {
        const int r = g * 16 + i;
        lds[r][cc] = W[(k0 + r) * CH + cc];
    }
    __syncthreads();
    const int k = k0 + cc;
#pragma unroll
    for (int i = 0; i < 16; ++i) {
        const int c = g * 16 + i;
        wt2[((long)(k >> 5) * 192 + (m * 64 + c)) * 32 + (k & 31)] = f2bf(lds[cc][c]);
    }
}

// ---------------- projection: LDS GEMM, BM=32 x BN=192 x BK=64 ----------------
// Double-buffered LDS, ONE barrier per K-step; reg-prefetch one step ahead.
__global__ __launch_bounds__(512)
void proj_mfma(const float* __restrict__ x, const ushort_t* __restrict__ wt2,
               ushort_t* __restrict__ qb, ushort_t* __restrict__ kb, ushort_t* __restrict__ vb)
{
    const int tid = threadIdx.x;
    const int w = tid >> 6, l = tid & 63, lg = l >> 4, lr = l & 15;
    const int wr = w >> 2, wc = w & 3;
    const long t0 = (long)blockIdx.x * 32;

    __shared__ ushort_t As[2][32][68];
    __shared__ ushort_t Bs[2][192][68];

    f32x4 acc[3];
#pragma unroll
    for (int nf = 0; nf < 3; ++nf) acc[nf] = (f32x4){0.f, 0.f, 0.f, 0.f};

    const int arow = tid >> 4, acol = (tid & 15) * 4;
    const float* __restrict__ xsrc = x + (t0 + arow) * CE + acol;

    int bc[3], bh[3], bk[3];
#pragma unroll
    for (int i = 0; i < 3; ++i) {
        const int idx = i * 512 + tid;
        const int h = idx >= 768;
        const int j = idx - h * 768;
        bc[i] = j >> 2; bh[i] = h; bk[i] = (j & 3) * 8;
    }

    // prologue: step0 -> LDS buf0; step1 -> regs
    float4 a4 = *(const float4*)(xsrc);
    u16x8 bv[3];
#pragma unroll
    for (int i = 0; i < 3; ++i)
        bv[i] = *(const u16x8*)(wt2 + ((long)(bh[i]) * 192 + bc[i]) * 32 + bk[i]);
    {
        uint2 pk;
        pk.x = cvt_pk_bf16(a4.x, a4.y);
        pk.y = cvt_pk_bf16(a4.z, a4.w);
        *(uint2*)&As[0][arow][acol] = pk;
#pragma unroll
        for (int i = 0; i < 3; ++i) {
            union { u16x8 v; uint2 q[2]; } uu; uu.v = bv[i];
            ushort_t* d = &Bs[0][bc[i]][bh[i] * 32 + bk[i]];
            *(uint2*)d = uu.q[0];
            *(uint2*)(d + 4) = uu.q[1];
        }
    }
    a4 = *(const float4*)(xsrc + 64);
#pragma unroll
    for (int i = 0; i < 3; ++i)
        bv[i] = *(const u16x8*)(wt2 + ((long)(2 + bh[i]) * 192 + bc[i]) * 32 + bk[i]);
    __syncthreads();

    for (int step = 0; step < 16; ++step) {
        const int cur = step & 1;
        if (step + 1 < 16) {
            uint2 pk;
            pk.x = cvt_pk_bf16(a4.x, a4.y);
            pk.y = cvt_pk_bf16(a4.z, a4.w);
            *(uint2*)&As[cur ^ 1][arow][acol] = pk;
#pragma unroll
            for (int i = 0; i < 3; ++i) {
                union { u16x8 v; uint2 q[2]; } uu; uu.v = bv[i];
                ushort_t* d = &Bs[cur ^ 1][bc[i]][bh[i] * 32 + bk[i]];
                *(uint2*)d = uu.q[0];
                *(uint2*)(d + 4) = uu.q[1];
            }
        }
        if (step + 2 < 16) {
            a4 = *(const float4*)(xsrc + (step + 2) * 64);
            const int ktn = (step + 2) * 2;
#pragma unroll
            for (int i = 0; i < 3; ++i)
                bv[i] = *(const u16x8*)(wt2 + ((long)(ktn + bh[i]) * 192 + bc[i]) * 32 + bk[i]);
        }
#pragma unroll
        for (int h = 0; h < 2; ++h) {
            bf16x8 af = frag68(&As[cur][wr * 16 + lr][h * 32 + lg * 8]);
#pragma unroll
            for (int nf = 0; nf < 3; ++nf) {
                bf16x8 bf = frag68(&Bs[cur][wc * 48 + nf * 16 + lr][h * 32 + lg * 8]);
                acc[nf] = __builtin_amdgcn_mfma_f32_16x16x32_bf16(af, bf, acc[nf], 0, 0, 0);
            }
        }
        __syncthreads();   // single barrier: next buf published, cur-buf reads drained
    }

    ushort_t* Os = &Bs[0][0][0];
#pragma unroll
    for (int nf = 0; nf < 3; ++nf)
#pragma unroll
        for (int r = 0; r < 4; ++r)
            Os[(wr * 16 + lg * 4 + r) * 200 + wc * 48 + nf * 16 + lr] = f2bf(acc[nf][r]);
    __syncthreads();
    if (tid < 256) {
        const int row = tid >> 3, c0 = (tid & 7) * 8;
#pragma unroll
        for (int m = 0; m < 3; ++m) {
            u16x8 ov = *(const u16x8*)&Os[row * 200 + m * 64 + c0];
            ushort_t* __restrict__ outp = (m == 0) ? kb : (m == 1 ? qb : vb);
            *(u16x8*)(outp + (t0 + row) * CH + c0) = ov;
        }
    }
}

// ---------------- pass 1: per-column (k) expsum, 8 waves = 2 j-groups x 4 k-slices ----------------
// grid (BB, 32, NZC): kt pair (p, 63-p); group wg takes j = j0 + NZC*wg + 2*NZC*i.
__global__ __launch_bounds__(512)
void colstats_mfma(const ushort_t* __restrict__ qb, const ushort_t* __restrict__ kb,
                   float* __restrict__ pl)
{
    const int b = blockIdx.x, p = blockIdx.y, z = blockIdx.z;
    const int tid = threadIdx.x;
    const int w = tid >> 6, l = tid & 63, lg = l >> 4, lr = l & 15;
    const int wg = w >> 2, wc = w & 3, tg = tid & 255;
    const long baseT = (long)b * TT;
    const long NTT = (long)BB * TT;

    __shared__ ushort_t Ks[64][68], Qs[2][64][68];
    __shared__ float redc[4][64][5];

    for (int pass = 0; pass < 2; ++pass) {
        const int kt = pass ? (63 - p) : p;
        stage_tile512(kb + (baseT + (long)kt * 64) * CH, Ks, tid);
        __syncthreads();
        bf16x8 ka0 = frag68(&Ks[wc * 16 + lr][lg * 8]);
        bf16x8 ka1 = frag68(&Ks[wc * 16 + lr][32 + lg * 8]);

        float l_r[4] = {0.f, 0.f, 0.f, 0.f};

        const int j0 = kt + ((z - kt) & (NZC - 1));
        const int n0 = (j0 < NQT) ? ((NQT - 1 - j0) >> 4) + 1 : 0;   // stride 2*NZC = 16
        for (int i = 0; i < n0; ++i) {
            const int j = j0 + NZC * wg + 2 * NZC * i;
            const bool act = (j < NQT);
            if (act) stage_tile(qb + (baseT + (long)j * 64) * CH, Qs[wg], tg);
            __syncthreads();   // B1: Qs ready
            if (act) {
                const bool diag = (j == kt);
#pragma unroll
                for (int qf = 0; qf < 4; ++qf) {
                    bf16x8 b0 = frag68(&Qs[wg][qf * 16 + lr][lg * 8]);
                    bf16x8 b1 = frag68(&Qs[wg][qf * 16 + lr][32 + lg * 8]);
                    f32x4 s = {0.f, 0.f, 0.f, 0.f};
                    s = __builtin_amdgcn_mfma_f32_16x16x32_bf16(ka0, b0, s, 0, 0, 0);
                    s = __builtin_amdgcn_mfma_f32_16x16x32_bf16(ka1, b1, s, 0, 0, 0);
#pragma unroll
                    for (int r = 0; r < 4; ++r) {
                        float ev = exp2f(s[r] * SCALE2);
                        if (diag && (qf * 16 + lr) < (wc * 16 + lg * 4 + r)) ev = 0.f;
                        l_r[r] += ev;
                    }
                }
            }
            __syncthreads();   // B2: Qs reads drained before next stage
        }
        // combine the 2 j-groups, then sum over the 16-lane q dimension
        if (wg == 1) {
#pragma unroll
            for (int r = 0; r < 4; ++r) redc[wc][l][r] = l_r[r];
        }
        __syncthreads();
        if (wg == 0) {
#pragma unroll
            for (int r = 0; r < 4; ++r) {
                float lv = l_r[r] + redc[wc][l][r];
                for (int d = 1; d < 16; d <<= 1) lv += __shfl_xor(lv, d);
                if (lr == 0) {
                    const long k = (long)kt * 64 + wc * 16 + lg * 4 + r;
                    pl[(long)z * NTT + baseT + k] = lv;
                }
            }
        }
        __syncthreads();   // redc safe for next pass
    }
}

// ---------------- vtb2[b][jtile][c][t] = v[t][c] / sum_z pl[z][t]  (bf16, tile-major) ----------------
__global__ __launch_bounds__(256)
void vt_scale(const ushort_t* __restrict__ vb, const float* __restrict__ pl,
              ushort_t* __restrict__ vtb2)
{
    const int b = blockIdx.x;
    const int jt = blockIdx.y;
    const long t0 = (long)jt * 64;
    const int tid = threadIdx.x;
    __shared__ ushort_t lds[64][72];
    const long baseT = (long)b * TT;
    const long NTT = (long)BB * TT;
#pragma unroll
    for (int i = 0; i < 2; ++i) {
        const int t = i * 32 + (tid >> 3);
        const int c0 = (tid & 7) * 8;
        u16x8 v = *(const u16x8*)(vb + (baseT + t0 + t) * CH + c0);
        const long idx = baseT + t0 + t;
        float ls = pl[idx];
#pragma unroll
        for (int zz = 1; zz < NZC; ++zz) ls += pl[zz * NTT + idx];
        const float sc = 1.f / ls;
#pragma unroll
        for (int j = 0; j < 8; ++j) lds[c0 + j][t] = f2bf(bf2f(v[j]) * sc);
    }
    __syncthreads();
    ushort_t* __restrict__ dst = vtb2 + ((long)(b * 64 + jt)) * (64 * 64);
#pragma unroll
    for (int i = 0; i < 2; ++i) {
        const int c = i * 32 + (tid >> 3);
        const int tt0 = (tid & 7) * 8;
        u16x8 ov = *(const u16x8*)&lds[c][tt0];
        *(u16x8*)(dst + (long)c * 64 + tt0) = ov;
    }
}

// ---------------- pass 2: O^T partials (bf16), 8 waves = 2 j-groups x 4 slices ----------------
// grid (BB, 32, NZP).
__global__ __launch_bounds__(512)
void pv_mfma(const ushort_t* __restrict__ qb, const ushort_t* __restrict__ kb,
             const ushort_t* __restrict__ vtb2, ushort_t* __restrict__ pout)
{
    const int b = blockIdx.x, p = blockIdx.y, z = blockIdx.z;
    const int tid = threadIdx.x;
    const int w = tid >> 6, l = tid & 63, lg = l >> 4, lr = l & 15;
    const int wg = w >> 2, wc = w & 3, tg = tid & 255;
    const long baseT = (long)b * TT;
    const long NTT = (long)BB * TT;

    __shared__ ushort_t Qs[64][68], Ks[2][64][68], Vs[2][64][68], Ps[2][64][68];
    __shared__ float redp[4][64][17];

    for (int pass = 0; pass < 2; ++pass) {
        const int qt = pass ? (63 - p) : p;
        stage_tile512(qb + (baseT + (long)qt * 64) * CH, Qs, tid);
        __syncthreads();
        bf16x8 qf_[4][2];
#pragma unroll
        for (int qf = 0; qf < 4; ++qf) {
            qf_[qf][0] = frag68(&Qs[qf * 16 + lr][lg * 8]);
            qf_[qf][1] = frag68(&Qs[qf * 16 + lr][32 + lg * 8]);
        }
        f32x4 o[4];
#pragma unroll
        for (int qf = 0; qf < 4; ++qf) o[qf] = (f32x4){0.f, 0.f, 0.f, 0.f};

        const int n0 = (qt >= z) ? ((qt - z) >> 3) + 1 : 0;
        for (int i = 0; i < n0; ++i) {
            const int j = z + 4 * wg + 8 * i;
            const bool act = (j <= qt);
            if (act) {
                stage_tile(kb + (baseT + (long)j * 64) * CH, Ks[wg], tg);
                stage_tile(vtb2 + ((long)(b * 64 + j)) * (64 * 64), Vs[wg], tg);
            }
            __syncthreads();   // B1: Ks/Vs ready
            bf16x8 va0, va1;
            if (act) {
                bf16x8 ka0 = frag68(&Ks[wg][wc * 16 + lr][lg * 8]);
                bf16x8 ka1 = frag68(&Ks[wg][wc * 16 + lr][32 + lg * 8]);
                va0 = frag68(&Vs[wg][wc * 16 + lr][lg * 8]);
                va1 = frag68(&Vs[wg][wc * 16 + lr][32 + lg * 8]);
                const bool diag = (j == qt);
#pragma unroll
                for (int qf = 0; qf < 4; ++qf) {
                    f32x4 s = {0.f, 0.f, 0.f, 0.f};
                    s = __builtin_amdgcn_mfma_f32_16x16x32_bf16(ka0, qf_[qf][0], s, 0, 0, 0);
                    s = __builtin_amdgcn_mfma_f32_16x16x32_bf16(ka1, qf_[qf][1], s, 0, 0, 0);
                    float ev[4];
#pragma unroll
                    for (int r = 0; r < 4; ++r) {
                        ev[r] = exp2f(s[r] * SCALE2);
                        if (diag && (qf * 16 + lr) < (wc * 16 + lg * 4 + r)) ev[r] = 0.f;
                    }
                    uint2 pk;
                    pk.x = cvt_pk_bf16(ev[0], ev[1]);
                    pk.y = cvt_pk_bf16(ev[2], ev[3]);
                    *(uint2*)&Ps[wg][qf * 16 + lr][wc * 16 + lg * 4] = pk;
                }
            }
            __syncthreads();   // B2: Ps ready (Ks/Vs reg-loads drained)
            if (act) {
#pragma unroll
                for (int qf = 0; qf < 4; ++qf) {
                    bf16x8 p0 = frag68(&Ps[wg][qf * 16 + lr][lg * 8]);
                    bf16x8 p1 = frag68(&Ps[wg][qf * 16 + lr][32 + lg * 8]);
                    o[qf] = __builtin_amdgcn_mfma_f32_16x16x32_bf16(va0, p0, o[qf], 0, 0, 0);
                    o[qf] = __builtin_amdgcn_mfma_f32_16x16x32_bf16(va1, p1, o[qf], 0, 0, 0);
                }
            }
        }
        // combine the 2 j-groups' partial O, then store as bf16
        if (wg == 1) {
#pragma unroll
            for (int qf = 0; qf < 4; ++qf)
#pragma unroll
                for (int r = 0; r < 4; ++r) redp[wc][l][qf * 4 + r] = o[qf][r];
        }
        __syncthreads();
        if (wg == 0) {
            ushort_t* pz = pout + ((long)z * NTT + baseT + (long)qt * 64) * CH;
#pragma unroll
            for (int qf = 0; qf < 4; ++qf) {
                f32x4 ov = o[qf];
#pragma unroll
                for (int r = 0; r < 4; ++r) ov[r] += redp[wc][l][qf * 4 + r];
                uint2 pk;
                pk.x = cvt_pk_bf16(ov[0], ov[1]);
                pk.y = cvt_pk_bf16(ov[2], ov[3]);
                *(uint2*)(pz + (long)(qf * 16 + lr) * CH + wc * 16 + lg * 4) = pk;
            }
        }
        __syncthreads();   // redp safe for next pass
    }
}

// ---------------- sum the NZP bf16 partial outputs -> f32 ----------------
__global__ __launch_bounds__(256)
void finalize_out(const ushort_t* __restrict__ pout, float* __restrict__ out)
{
    const long i = (long)blockIdx.x * 256 + threadIdx.x;   // index over groups of 4 elems
    const long ne = (long)BB * TT * CH;                    // elems per partial
    float s0 = 0.f, s1 = 0.f, s2 = 0.f, s3 = 0.f;
#pragma unroll
    for (int zz = 0; zz < NZP; ++zz) {
        uint2 a = *(const uint2*)(pout + zz * ne + i * 4);
        s0 += bf2f((unsigned short)(a.x & 0xffffu));
        s1 += bf2f((unsigned short)(a.x >> 16));
        s2 += bf2f((unsigned short)(a.y & 0xffffu));
        s3 += bf2f((unsigned short)(a.y >> 16));
    }
    float4 r; r.x = s0; r.y = s1; r.z = s2; r.w = s3;
    reinterpret_cast<float4*>(out)[i] = r;
}

extern "C" void kernel_launch(void* const* d_in, const int* in_sizes, int n_in,
                              void* d_out, int out_size, void* d_ws, size_t ws_size,
                              hipStream_t stream)
{
    const float* x  = (const float*)d_in[0];
    const float* Wk = (const float*)d_in[1];
    const float* Wq = (const float*)d_in[2];
    const float* Wv = (const float*)d_in[3];
    float* out = (float*)d_out;

    const size_t NT = (size_t)BB * TT;   // 16384
    ushort_t* qb   = (ushort_t*)d_ws;    // NT*CH bf16
    ushort_t* kb   = qb + NT * CH;
    ushort_t* vb   = kb + NT * CH;
    ushort_t* vtb2 = vb + NT * CH;
    ushort_t* wt2  = vtb2 + NT * CH;        // 192*1024 bf16
    float* pl      = (float*)(wt2 + 192 * CE);   // NZC*NT f32
    ushort_t* pout = (ushort_t*)(pl + NZC * NT); // NZP*NT*CH bf16

    hipLaunchKernelGGL(wt_build, dim3(3, 16), dim3(256), 0, stream,
                       Wk, Wq, Wv, wt2);
    hipLaunchKernelGGL(proj_mfma, dim3(NT / 32), dim3(512), 0, stream,
                       x, wt2, qb, kb, vb);
    hipLaunchKernelGGL(colstats_mfma, dim3(BB, NQT / 2, NZC), dim3(512), 0, stream,
                       qb, kb, pl);
    hipLaunchKernelGGL(vt_scale, dim3(BB, TT / 64), dim3(256), 0, stream,
                       vb, pl, vtb2);
    hipLaunchKernelGGL(pv_mfma, dim3(BB, NQT / 2, NZP), dim3(512), 0, stream,
                       qb, kb, vtb2, pout);
    hipLaunchKernelGGL(finalize_out, dim3(NT * CH / 4 / 256), dim3(256), 0, stream,
                       pout, out);
}